// Round 11
// baseline (502.270 us; speedup 1.0000x reference)
//
#include <hip/hip_runtime.h>
#include <hip/hip_fp16.h>
#include <cstdint>

#define HIDDEN 128
#define MTOT 16
#define EPG 5  // edges per 16-lane group (E=1.6M, NB=20000 -> 320000 groups)

typedef float vfloat4 __attribute__((ext_vector_type(4)));

// ---------------------------------------------------------------------------
// Zero-fill d_out (harness poisons d_out with 0xAA; graph must re-zero).
// ---------------------------------------------------------------------------
__global__ __launch_bounds__(256) void zero_kernel(float4* __restrict__ out,
                                                   int n4) {
  int i = blockIdx.x * 256 + threadIdx.x;
  int stride = gridDim.x * 256;
  float4 z = {0.f, 0.f, 0.f, 0.f};
  for (; i < n4; i += stride) out[i] = z;
}

// ---------------------------------------------------------------------------
// q/k projection, fp16 output. W in LDS, float4-preserving XOR swizzle.
// 8-row unroll: one ds_read_b128 feeds 32 FMAs.
// ---------------------------------------------------------------------------
__global__ __launch_bounds__(256) void proj_kernel(
    const float* __restrict__ x, const float* __restrict__ W,
    __half* __restrict__ out, int n_rows, float scale) {
  __shared__ float sW[128 * 128];  // 64 KB, swizzled
  for (int i = threadIdx.x; i < 128 * 128; i += 256) {
    int j = i >> 7, d = i & 127;
    sW[j * 128 + (d ^ ((j & 7) << 2))] = W[i] * scale;
  }
  __syncthreads();

  const int col = threadIdx.x & 127;
  const int g   = threadIdx.x >> 7;
  const int sx  = (col & 7) << 2;
  const float* sWc = sW + col * 128;

  const int row0 = blockIdx.x * 64;
#pragma unroll 1
  for (int m = 0; m < 4; ++m) {
    int r0 = row0 + g * 8 + m * 16;
    if (r0 >= n_rows) break;
    const float4* x4 = (const float4*)(x + (size_t)r0 * HIDDEN);
    if (r0 + 7 < n_rows) {
      float a0 = 0.f, a1 = 0.f, a2 = 0.f, a3 = 0.f;
      float a4 = 0.f, a5 = 0.f, a6 = 0.f, a7 = 0.f;
#pragma unroll
      for (int d4 = 0; d4 < 32; ++d4) {
        float4 w4 = *(const float4*)(sWc + ((d4 << 2) ^ sx));
        float4 xv0 = x4[d4];
        float4 xv1 = x4[32 + d4];
        float4 xv2 = x4[64 + d4];
        float4 xv3 = x4[96 + d4];
        float4 xv4 = x4[128 + d4];
        float4 xv5 = x4[160 + d4];
        float4 xv6 = x4[192 + d4];
        float4 xv7 = x4[224 + d4];
        a0 += xv0.x * w4.x + xv0.y * w4.y + xv0.z * w4.z + xv0.w * w4.w;
        a1 += xv1.x * w4.x + xv1.y * w4.y + xv1.z * w4.z + xv1.w * w4.w;
        a2 += xv2.x * w4.x + xv2.y * w4.y + xv2.z * w4.z + xv2.w * w4.w;
        a3 += xv3.x * w4.x + xv3.y * w4.y + xv3.z * w4.z + xv3.w * w4.w;
        a4 += xv4.x * w4.x + xv4.y * w4.y + xv4.z * w4.z + xv4.w * w4.w;
        a5 += xv5.x * w4.x + xv5.y * w4.y + xv5.z * w4.z + xv5.w * w4.w;
        a6 += xv6.x * w4.x + xv6.y * w4.y + xv6.z * w4.z + xv6.w * w4.w;
        a7 += xv7.x * w4.x + xv7.y * w4.y + xv7.z * w4.z + xv7.w * w4.w;
      }
      out[(size_t)(r0 + 0) * HIDDEN + col] = __float2half(a0);
      out[(size_t)(r0 + 1) * HIDDEN + col] = __float2half(a1);
      out[(size_t)(r0 + 2) * HIDDEN + col] = __float2half(a2);
      out[(size_t)(r0 + 3) * HIDDEN + col] = __float2half(a3);
      out[(size_t)(r0 + 4) * HIDDEN + col] = __float2half(a4);
      out[(size_t)(r0 + 5) * HIDDEN + col] = __float2half(a5);
      out[(size_t)(r0 + 6) * HIDDEN + col] = __float2half(a6);
      out[(size_t)(r0 + 7) * HIDDEN + col] = __float2half(a7);
    } else {
      for (int r = r0; r < n_rows; ++r) {
        const float4* xr = (const float4*)(x + (size_t)r * HIDDEN);
        float a = 0.f;
        for (int d4 = 0; d4 < 32; ++d4) {
          float4 w4 = *(const float4*)(sWc + ((d4 << 2) ^ sx));
          float4 xv = xr[d4];
          a += xv.x * w4.x + xv.y * w4.y + xv.z * w4.z + xv.w * w4.w;
        }
        out[(size_t)r * HIDDEN + col] = __float2half(a);
      }
    }
  }
}

// ---------------------------------------------------------------------------
// Edge kernel, 16 LANES PER EDGE (VMEM-instruction-rate attack).
// A wave carries 4 edges per memory instruction:
//   q,k: one dwordx4 per lane (16 lanes x 16B = full 256B fp16 row per edge)
//   w:   two dwordx4 per lane
//   sph: one dword per lane (m = lane&15)
//   atomics: ONE wave inst, all 64 lanes active (no idle scatter half)
// Index preamble: lanes 0..14 load the group's 5 (src,dst,cutoff) triples in
// ONE VMEM inst per field-set; redistributed by shfl -> ~0.05 inst/edge.
// Per-edge VMEM insts: ~1.5 vs ~4.4 in the 32-lane version (2.9x fewer).
// Each group owns 5 CONTIGUOUS edges; XCD-swizzle keeps per-L2 windows dense.
// ---------------------------------------------------------------------------
__global__ __launch_bounds__(256) void edge_kernel(
    const __half* __restrict__ q, const __half* __restrict__ k,
    const float* __restrict__ w_ij, const float* __restrict__ sph,
    const int* __restrict__ ei, const float* __restrict__ cutoff,
    float* __restrict__ out, int E, int nb8) {
  const int rank = (blockIdx.x & 7) * nb8 + (blockIdx.x >> 3);
  const int gid  = rank * 16 + (threadIdx.x >> 4);   // global 16-lane group id
  const int eb   = gid * EPG;                        // first edge of group
  if (eb >= E) return;

  const int wl  = threadIdx.x & 63;  // lane in wave
  const int idx = wl & 15;           // lane in group = m component
  const int gb  = wl & 48;           // group base lane in wave
  // m -> head: m0->h0, m1..3->h1, m4..8->h2, m9..15->h3
  const int h_for_m = (idx >= 1) + (idx >= 4) + (idx >= 9);
  const int amLane  = gb + (h_for_m << 2);  // head h alphas live at gb+4h..+3

  // --- preamble: one load per lane covers all 5 triples of this group ---
  // lanes 0-4: src[t], lanes 5-9: dst[t], lanes 10-14: cutoff[t]
  int f = (idx >= 5) + (idx >= 10);
  int t0 = idx - f * 5;
  if (t0 > EPG - 1) t0 = EPG - 1;            // lane 15 -> harmless dup
  int te = eb + t0;
  if (te > E - 1) te = E - 1;
  uint32_t pre;
  if (f == 0)      pre = (uint32_t)__builtin_nontemporal_load(ei + te);
  else if (f == 1) pre = (uint32_t)__builtin_nontemporal_load(ei + E + te);
  else             pre = __float_as_uint(__builtin_nontemporal_load(cutoff + te));

#pragma unroll
  for (int t = 0; t < EPG; ++t) {
    const int e = eb + t;
    if (e >= E) break;
    const int src = __shfl((int)pre, gb + t);
    const int dst = __shfl((int)pre, gb + 5 + t);
    const float cut = __uint_as_float((uint32_t)__shfl((int)pre, gb + 10 + t));

    // full rows: q/k 16B per lane, w 32B per lane
    const vfloat4* wp = (const vfloat4*)(w_ij + (size_t)e * HIDDEN) + idx * 2;
    vfloat4 w0 = __builtin_nontemporal_load(wp);
    vfloat4 w1 = __builtin_nontemporal_load(wp + 1);
    union { uint4 u; __half2 h2[4]; } qa, ka;
    qa.u = *((const uint4*)(q + (size_t)dst * HIDDEN) + idx);
    ka.u = *((const uint4*)(k + (size_t)src * HIDDEN) + idx);

    float2 q0 = __half22float2(qa.h2[0]);
    float2 q1 = __half22float2(qa.h2[1]);
    float2 q2 = __half22float2(qa.h2[2]);
    float2 q3 = __half22float2(qa.h2[3]);
    float2 k0 = __half22float2(ka.h2[0]);
    float2 k1 = __half22float2(ka.h2[1]);
    float2 k2 = __half22float2(ka.h2[2]);
    float2 k3 = __half22float2(ka.h2[3]);

    float p = q0.x * w0.x * k0.x + q0.y * w0.y * k0.y +
              q1.x * w0.z * k1.x + q1.y * w0.w * k1.y +
              q2.x * w1.x * k2.x + q2.y * w1.y * k2.y +
              q3.x * w1.z * k3.x + q3.y * w1.w * k3.y;
    // reduce over the 4 lanes of each head (32 dims)
    p += __shfl_xor(p, 1);
    p += __shfl_xor(p, 2);
    float alpha = p * cut;
    float am = __shfl(alpha, amLane);

    float s = __builtin_nontemporal_load(sph + (size_t)e * MTOT + idx);
    atomicAdd(out + (size_t)dst * MTOT + idx, am * s);
  }
}

extern "C" void kernel_launch(void* const* d_in, const int* in_sizes, int n_in,
                              void* d_out, int out_size, void* d_ws, size_t ws_size,
                              hipStream_t stream) {
  // inputs: chi, sph_ij, x, w_ij, edge_index, cutoff, Wq, Wk
  const float* sph    = (const float*)d_in[1];
  const float* x      = (const float*)d_in[2];
  const float* w_ij   = (const float*)d_in[3];
  const int*   ei     = (const int*)d_in[4];
  const float* cutoff = (const float*)d_in[5];
  const float* Wq     = (const float*)d_in[6];
  const float* Wk     = (const float*)d_in[7];
  float* out = (float*)d_out;

  const int n_nodes = in_sizes[0] / MTOT;  // chi is [N, 16]
  const int E       = in_sizes[5];         // cutoff is [E, 1]

  __half* q = (__half*)d_ws;
  __half* k = q + (size_t)n_nodes * HIDDEN;

  const int n4 = out_size / 4;
  zero_kernel<<<256, 256, 0, stream>>>((float4*)out, n4);

  const int pgrid = (n_nodes + 63) / 64;
  const float inv_sqrt_hd = 0.17677669529663687f;  // 1/sqrt(32)
  proj_kernel<<<pgrid, 256, 0, stream>>>(x, Wq, q, n_nodes, inv_sqrt_hd);
  proj_kernel<<<pgrid, 256, 0, stream>>>(x, Wk, k, n_nodes, 1.0f);

  // 16 groups/block x 5 edges = 80 edges/block; 20000 blocks covers 1.6M
  const int NB = (E + 79) / 80;
  const int NB8 = (NB + 7) / 8;
  edge_kernel<<<NB8 * 8, 256, 0, stream>>>(q, k, w_ij, sph, ei, cutoff, out,
                                           E, NB8);
}